// Round 1
// baseline (222.658 us; speedup 1.0000x reference)
//
#include <hip/hip_runtime.h>

// Shapes (fixed by the reference setup)
#define I_DIM 1024
#define J_DIM 1024
#define H_DIM 32
#define B_DIM 1024
#define INV_I1 (1.0f/1023.0f)
#define INV_J1 (1.0f/1023.0f)

// ws layout (float offsets)
#define WS_CW     0         // colsum(weight)        [1024]
#define WS_RW     1024      // rowsum(weight)        [1024]
#define WS_CH     2048      // colsum(hidden) (J,H)  [32768]
#define WS_RH     34816     // rowsum(hidden) (I,H)  [32768]
#define WS_PJ     67584     // per-j layer1 partial  [1024*10]
#define WS_QI     77824     // per-i layer1 partial (incl b1) [1024*10]
#define WS_LOGITS 88064     // X @ new_weight        [1024*1024]

// ---------------------------------------------------------------------------
// Kernel 1: all four reductions in one launch (role dispatched by blockIdx.x)
//  blocks [0,1024):    rowsum_h, one i per block (reads 128KB coalesced)
//  blocks [1024,1536): colsum_h, 64 cols x 4 i-quarters per block
//  blocks [1536,1664): rowsum_w, 8 rows per block (wave shuffle reduce)
//  blocks [1664,1668): colsum_w, 256 cols per block
// ---------------------------------------------------------------------------
__global__ __launch_bounds__(256) void k_reduce(const float* __restrict__ W,
                                                const float* __restrict__ Hd,
                                                float* __restrict__ ws) {
  __shared__ float4 s4[256];
  __shared__ float  s1[256];
  int b = blockIdx.x, t = threadIdx.x;
  if (b < 1024) {
    // rowsum_h[i=b][h], h-group = t % 8 (each float4 covers h=(t%8)*4..+3)
    const float4* row = (const float4*)(Hd + (size_t)b * (J_DIM * H_DIM));
    float4 acc = make_float4(0.f, 0.f, 0.f, 0.f);
    #pragma unroll
    for (int m = 0; m < 32; m++) {
      float4 v = row[t + 256 * m];
      acc.x += v.x; acc.y += v.y; acc.z += v.z; acc.w += v.w;
    }
    s4[t] = acc;
    __syncthreads();
    for (int off = 128; off >= 8; off >>= 1) {
      if (t < off) {
        float4 o = s4[t + off];
        float4 a = s4[t];
        a.x += o.x; a.y += o.y; a.z += o.z; a.w += o.w;
        s4[t] = a;
      }
      __syncthreads();
    }
    if (t < 8) ((float4*)(ws + WS_RH))[b * 8 + t] = s4[t];
  } else if (b < 1536) {
    // colsum_h over flattened (J*H)=32768 columns; block owns 64 cols
    int idx = b - 1024;
    int col = idx * 64 + (t & 63);
    int iq  = t >> 6;
    float acc = 0.f;
    for (int i = iq * 256; i < (iq + 1) * 256; i++)
      acc += Hd[(size_t)i * (J_DIM * H_DIM) + col];
    s1[t] = acc;
    __syncthreads();
    if (t < 128) s1[t] += s1[t + 128];
    __syncthreads();
    if (t < 64) ws[WS_CH + idx * 64 + t] = s1[t] + s1[t + 64];
  } else if (b < 1664) {
    // rowsum_w: 8 rows per block, 2 rows per wave
    int rb = b - 1536;
    int wv = t >> 6, lane = t & 63;
    for (int rr = 0; rr < 2; rr++) {
      int row = rb * 8 + wv * 2 + rr;
      float acc = 0.f;
      #pragma unroll
      for (int m = 0; m < 16; m++) acc += W[row * J_DIM + lane + 64 * m];
      #pragma unroll
      for (int off = 32; off > 0; off >>= 1) acc += __shfl_down(acc, off, 64);
      if (lane == 0) ws[WS_RW + row] = acc;
    }
  } else {
    // colsum_w: 256 cols per block
    int col = (b - 1664) * 256 + t;
    float acc = 0.f;
    for (int i = 0; i < I_DIM; i++) acc += W[i * J_DIM + col];
    ws[WS_CW + col] = acc;
  }
}

// ---------------------------------------------------------------------------
// Kernel 2: per-j (Pj) and per-i (Qi, includes b1) layer-1 partials
// ---------------------------------------------------------------------------
__global__ __launch_bounds__(256) void k_pq(const float* __restrict__ W1,
                                            const float* __restrict__ b1,
                                            float* __restrict__ ws) {
  int gid = blockIdx.x * 256 + threadIdx.x;
  float out[10];
  if (gid < 1024) {
    int j = gid;
    float sc = ws[WS_CW + j] * INV_I1;
    #pragma unroll
    for (int q = 0; q < 10; q++) out[q] = sc * W1[10 + q];
    for (int k = 0; k < 32; k++) {
      float c = ws[WS_CH + j * 32 + k] * INV_I1;
      #pragma unroll
      for (int q = 0; q < 10; q++) out[q] += c * W1[(35 + k) * 10 + q];
    }
    #pragma unroll
    for (int q = 0; q < 10; q++) ws[WS_PJ + j * 10 + q] = out[q];
  } else {
    int i = gid - 1024;
    float sr = ws[WS_RW + i] * INV_J1;
    #pragma unroll
    for (int q = 0; q < 10; q++) out[q] = b1[q] + sr * W1[20 + q];
    for (int k = 0; k < 32; k++) {
      float c = ws[WS_RH + i * 32 + k] * INV_J1;
      #pragma unroll
      for (int q = 0; q < 10; q++) out[q] += c * W1[(67 + k) * 10 + q];
    }
    #pragma unroll
    for (int q = 0; q < 10; q++) ws[WS_QI + i * 10 + q] = out[q];
  }
}

// ---------------------------------------------------------------------------
// Kernel 3: per-cell MLP. Block = one i-row half (512 cells), 2 cells/thread.
// Weights combined into A (33x10) and staged in LDS (broadcast reads).
// ---------------------------------------------------------------------------
__global__ __launch_bounds__(256, 2) void k_mlp(
    const float* __restrict__ W, const float* __restrict__ Hd,
    const float* __restrict__ W1, const float* __restrict__ W2,
    const float* __restrict__ b2, const float* __restrict__ W3,
    const float* __restrict__ b3, const float* __restrict__ ws,
    float* __restrict__ newW, float* __restrict__ newH) {
  __shared__ float Al[33][12];   // row 0: w coeff; rows 1..32: h coeffs
  __shared__ float W2l[10][12];  // W2l[q][q2]
  __shared__ float W3t[33][12];  // W3t[o][q2]
  __shared__ float b3l[33];
  __shared__ float b2l[10];
  int t = threadIdx.x;
  for (int idx = t; idx < 330; idx += 256) {
    int r = idx / 10, q = idx - r * 10;
    float v;
    if (r == 0)
      v = W1[q] - W1[10 + q] * INV_I1 - W1[20 + q] * INV_J1;
    else
      v = W1[(2 + r) * 10 + q] - W1[(34 + r) * 10 + q] * INV_I1 - W1[(66 + r) * 10 + q] * INV_J1;
    Al[r][q] = v;
  }
  for (int idx = t; idx < 100; idx += 256) W2l[idx / 10][idx - (idx / 10) * 10] = W2[idx];
  for (int idx = t; idx < 330; idx += 256) { int q2 = idx / 33, o = idx - q2 * 33; W3t[o][q2] = W3[idx]; }
  if (t < 33) b3l[t] = b3[t];
  if (t < 10) b2l[t] = b2[t];
  __syncthreads();

  int i = blockIdx.x >> 1;
  int j = (blockIdx.x & 1) * 512 + t;
  int cell0 = i * J_DIM + j;
  int cell1 = cell0 + 256;

  float qi[10];
  #pragma unroll
  for (int q = 0; q < 10; q++) qi[q] = ws[WS_QI + i * 10 + q];

  float h0[32], h1[32];
  #pragma unroll
  for (int m = 0; m < 8; m++) {
    float4 v = ((const float4*)Hd)[cell0 * 8 + m];
    h0[4*m] = v.x; h0[4*m+1] = v.y; h0[4*m+2] = v.z; h0[4*m+3] = v.w;
    float4 u = ((const float4*)Hd)[cell1 * 8 + m];
    h1[4*m] = u.x; h1[4*m+1] = u.y; h1[4*m+2] = u.z; h1[4*m+3] = u.w;
  }
  float w0 = W[cell0], w1 = W[cell1];

  const float* pj0 = ws + WS_PJ + j * 10;
  const float* pj1 = ws + WS_PJ + (j + 256) * 10;
  float z0[10], z1[10];
  #pragma unroll
  for (int q = 0; q < 10; q++) {
    z0[q] = pj0[q] + qi[q] + w0 * Al[0][q];
    z1[q] = pj1[q] + qi[q] + w1 * Al[0][q];
  }
  #pragma unroll
  for (int k = 0; k < 32; k++) {
    #pragma unroll
    for (int q = 0; q < 10; q++) {
      float a = Al[k + 1][q];
      z0[q] += h0[k] * a;
      z1[q] += h1[k] * a;
    }
  }
  #pragma unroll
  for (int q = 0; q < 10; q++) { z0[q] = fmaxf(z0[q], 0.f); z1[q] = fmaxf(z1[q], 0.f); }

  float y0[10], y1[10];
  #pragma unroll
  for (int q2 = 0; q2 < 10; q2++) { y0[q2] = b2l[q2]; y1[q2] = b2l[q2]; }
  #pragma unroll
  for (int q = 0; q < 10; q++) {
    #pragma unroll
    for (int q2 = 0; q2 < 10; q2++) {
      float wv = W2l[q][q2];
      y0[q2] += z0[q] * wv;
      y1[q2] += z1[q] * wv;
    }
  }
  #pragma unroll
  for (int q2 = 0; q2 < 10; q2++) { y0[q2] = fmaxf(y0[q2], 0.f); y1[q2] = fmaxf(y1[q2], 0.f); }

  // layer 3, o = 0 -> new_weight
  float u0 = b3l[0], u1 = b3l[0];
  #pragma unroll
  for (int q2 = 0; q2 < 10; q2++) { u0 += y0[q2] * W3t[0][q2]; u1 += y1[q2] * W3t[0][q2]; }
  newW[cell0] = w0 + u0;
  newW[cell1] = w1 + u1;

  // o = 1..32 -> new_hidden (accumulate in place, then vector store)
  #pragma unroll
  for (int o = 1; o < 33; o++) {
    float a0 = b3l[o], a1 = b3l[o];
    #pragma unroll
    for (int q2 = 0; q2 < 10; q2++) {
      float wv = W3t[o][q2];
      a0 += y0[q2] * wv;
      a1 += y1[q2] * wv;
    }
    h0[o - 1] += a0;
    h1[o - 1] += a1;
  }
  #pragma unroll
  for (int m = 0; m < 8; m++) {
    ((float4*)newH)[cell0 * 8 + m] = make_float4(h0[4*m], h0[4*m+1], h0[4*m+2], h0[4*m+3]);
    ((float4*)newH)[cell1 * 8 + m] = make_float4(h1[4*m], h1[4*m+1], h1[4*m+2], h1[4*m+3]);
  }
}

// ---------------------------------------------------------------------------
// Kernel 4: f32 GEMM  logits = X(1024x1024) @ newW(1024x1024)
// 64x64 tile, BK=16, 256 threads, 4x4 per thread, register prefetch.
// ---------------------------------------------------------------------------
__global__ __launch_bounds__(256) void k_gemm(const float* __restrict__ A,
                                              const float* __restrict__ B,
                                              float* __restrict__ C) {
  __shared__ float As[16][68];  // As[k][m]
  __shared__ float Bs[16][68];  // Bs[k][n]
  int t = threadIdx.x;
  int bm = blockIdx.y, bn = blockIdx.x;
  int ar = t >> 2, ak = (t & 3) << 2;     // A-tile loader: row, k-quad
  int bk = t >> 4, bnc = (t & 15) << 2;   // B-tile loader: k-row, n-quad
  int tm = (t >> 4) << 2, tn = (t & 15) << 2;
  const float* Ap = A + (bm * 64 + ar) * 1024 + ak;
  const float* Bp = B + bk * 1024 + bn * 64 + bnc;
  float acc[4][4] = {};
  float4 av = *(const float4*)Ap;
  float4 bv = *(const float4*)Bp;
  for (int k0 = 0; k0 < 1024; k0 += 16) {
    __syncthreads();
    As[ak + 0][ar] = av.x; As[ak + 1][ar] = av.y;
    As[ak + 2][ar] = av.z; As[ak + 3][ar] = av.w;
    *(float4*)&Bs[bk][bnc] = bv;
    __syncthreads();
    if (k0 + 16 < 1024) {
      av = *(const float4*)(Ap + k0 + 16);
      bv = *(const float4*)(Bp + (k0 + 16) * 1024);
    }
    #pragma unroll
    for (int kk = 0; kk < 16; kk++) {
      float4 a4 = *(const float4*)&As[kk][tm];
      float4 b4 = *(const float4*)&Bs[kk][tn];
      acc[0][0] += a4.x * b4.x; acc[0][1] += a4.x * b4.y; acc[0][2] += a4.x * b4.z; acc[0][3] += a4.x * b4.w;
      acc[1][0] += a4.y * b4.x; acc[1][1] += a4.y * b4.y; acc[1][2] += a4.y * b4.z; acc[1][3] += a4.y * b4.w;
      acc[2][0] += a4.z * b4.x; acc[2][1] += a4.z * b4.y; acc[2][2] += a4.z * b4.z; acc[2][3] += a4.z * b4.w;
      acc[3][0] += a4.w * b4.x; acc[3][1] += a4.w * b4.y; acc[3][2] += a4.w * b4.z; acc[3][3] += a4.w * b4.w;
    }
  }
  #pragma unroll
  for (int r = 0; r < 4; r++) {
    *(float4*)&C[(bm * 64 + tm + r) * 1024 + bn * 64 + tn] =
        make_float4(acc[r][0], acc[r][1], acc[r][2], acc[r][3]);
  }
}

// ---------------------------------------------------------------------------
// Kernel 5: row softmax, one block per row
// ---------------------------------------------------------------------------
__global__ __launch_bounds__(256) void k_softmax(const float* __restrict__ L,
                                                 float* __restrict__ P) {
  __shared__ float sm[4], ss[4];
  int r = blockIdx.x, t = threadIdx.x;
  const float* row = L + r * 1024;
  float v0 = row[t], v1 = row[t + 256], v2 = row[t + 512], v3 = row[t + 768];
  float m = fmaxf(fmaxf(v0, v1), fmaxf(v2, v3));
  #pragma unroll
  for (int off = 32; off > 0; off >>= 1) m = fmaxf(m, __shfl_xor(m, off, 64));
  int wv = t >> 6, lane = t & 63;
  if (lane == 0) sm[wv] = m;
  __syncthreads();
  m = fmaxf(fmaxf(sm[0], sm[1]), fmaxf(sm[2], sm[3]));
  float e0 = expf(v0 - m), e1 = expf(v1 - m), e2 = expf(v2 - m), e3 = expf(v3 - m);
  float s = e0 + e1 + e2 + e3;
  #pragma unroll
  for (int off = 32; off > 0; off >>= 1) s += __shfl_xor(s, off, 64);
  if (lane == 0) ss[wv] = s;
  __syncthreads();
  s = ss[0] + ss[1] + ss[2] + ss[3];
  float inv = 1.0f / s;
  float* prow = P + r * 1024;
  prow[t] = e0 * inv; prow[t + 256] = e1 * inv;
  prow[t + 512] = e2 * inv; prow[t + 768] = e3 * inv;
}

extern "C" void kernel_launch(void* const* d_in, const int* in_sizes, int n_in,
                              void* d_out, int out_size, void* d_ws, size_t ws_size,
                              hipStream_t stream) {
  const float* X  = (const float*)d_in[0];
  const float* W  = (const float*)d_in[1];
  const float* Hd = (const float*)d_in[2];
  const float* W1 = (const float*)d_in[3];
  const float* b1 = (const float*)d_in[4];
  const float* W2 = (const float*)d_in[5];
  const float* b2 = (const float*)d_in[6];
  const float* W3 = (const float*)d_in[7];
  const float* b3 = (const float*)d_in[8];
  float* out   = (float*)d_out;
  float* probs = out;                      // (B,J)
  float* newW  = out + 1024 * 1024;        // (I,J)
  float* newH  = out + 2 * 1024 * 1024;    // (I,J,H)
  float* ws = (float*)d_ws;

  k_reduce<<<1668, 256, 0, stream>>>(W, Hd, ws);
  k_pq<<<8, 256, 0, stream>>>(W1, b1, ws);
  k_mlp<<<2048, 256, 0, stream>>>(W, Hd, W1, W2, b2, W3, b3, ws, newW, newH);
  k_gemm<<<dim3(16, 16), 256, 0, stream>>>(X, newW, ws + WS_LOGITS);
  k_softmax<<<1024, 256, 0, stream>>>(ws + WS_LOGITS, probs);
}